// Round 6
// baseline (15733.531 us; speedup 1.0000x reference)
//
#include <hip/hip_runtime.h>
#include <hip/hip_bf16.h>

// Seq2seq GRU (2-layer enc T=192, 2-layer dec T=96), B=128, H=1024.
// Round 6: persistent kernel, NO threadfence (no L2 wbinv). Cross-block
// bf16 state uses agent-scope relaxed atomics (sc1, L2-bypass, coherent at
// L3); f32 master state is block-private (normal caching); weights stay
// L2-resident forever. LDS weight layout linearized to wave read order
// (conflict-free). Barrier: vmcnt drain + slot stores + master poll + flag.

#define H 1024
#define G 3072   /* 3*H */
#define BB 128
#define TENC 192
#define TDEC 96
#define NBLK 128
#define NSTEP 290   /* 193 enc + 97 dec diagonal steps */

typedef __attribute__((ext_vector_type(4))) float f32x4;
typedef __attribute__((ext_vector_type(8))) short bf16x8;

__device__ __forceinline__ float sigmoidf_(float x) {
    return 1.0f / (1.0f + __expf(-x));
}

__device__ __forceinline__ short f2bf_rne(float f) {
    union { float f; unsigned u; } v; v.f = f;
    unsigned r = v.u + 0x7fffu + ((v.u >> 16) & 1u);
    return (short)(r >> 16);
}

// agent-scope (sc1) 16B state load as 2 x u64 relaxed atomics
__device__ __forceinline__ bf16x8 ald16(const short* p) {
    const unsigned long long* q = (const unsigned long long*)p;
    unsigned long long a = __hip_atomic_load(q, __ATOMIC_RELAXED,
                                             __HIP_MEMORY_SCOPE_AGENT);
    unsigned long long b = __hip_atomic_load(q + 1, __ATOMIC_RELAXED,
                                             __HIP_MEMORY_SCOPE_AGENT);
    union { unsigned long long u[2]; bf16x8 v; } x;
    x.u[0] = a; x.u[1] = b;
    return x.v;
}

__global__ __launch_bounds__(256) void k_f2bf(const float* __restrict__ in,
                                              short* __restrict__ out, int n) {
    for (int i = blockIdx.x * 256 + threadIdx.x; i < n; i += gridDim.x * 256)
        out[i] = f2bf_rne(in[i]);
}

// dec_in[b][t][c]: t==0 -> x_enc[b][191][c], else x_dec[b][t-1][c]
__global__ __launch_bounds__(256) void k_build_decin(const float* __restrict__ x_enc,
                                                     const float* __restrict__ x_dec,
                                                     short* __restrict__ out) {
    int i = blockIdx.x * 256 + threadIdx.x;
    if (i >= BB * TDEC * 32) return;
    int c = i & 31;
    int t = (i >> 5) % TDEC;
    int b = i / (TDEC * 32);
    float v = (t == 0) ? x_enc[(size_t)b * TENC * 32 + 191 * 32 + c]
                       : x_dec[(size_t)b * TDEC * 32 + (t - 1) * 32 + c];
    out[i] = f2bf_rne(v);
}

// Persistent kernel. Blocks 0..63: L1 ("big") cell, i0=bid*16.
// Blocks 64..127: L0 ("small") cell, i0=(bid-64)*16.
// 16 waves: team tm = w>>1 (m-tile, 16 rows), kh = w&1 (K-half).
// LDS whh layout: [gate:3][khalf:2][kiter:16][lane:64]x16B (96 KB), linear
// in wave read order -> conflict-free ds_read_b128.
__global__ __launch_bounds__(1024) void k_persist(
    const short* __restrict__ xencbf, const short* __restrict__ decinbf,
    const short* __restrict__ wih0e, const short* __restrict__ whh0e,
    const float* __restrict__ ebih0, const float* __restrict__ ebhh0,
    const short* __restrict__ wih1e, const short* __restrict__ whh1e,
    const float* __restrict__ ebih1, const float* __restrict__ ebhh1,
    const short* __restrict__ wih0d, const short* __restrict__ whh0d,
    const float* __restrict__ dbih0, const float* __restrict__ dbhh0,
    const short* __restrict__ wih1d, const short* __restrict__ whh1d,
    const float* __restrict__ dbih1, const float* __restrict__ dbhh1,
    short* __restrict__ y0r, float* __restrict__ pp0,
    short* __restrict__ hbf1, float* __restrict__ pp1,
    float* __restrict__ y1, unsigned* __restrict__ barr)
{
    __shared__ short wlds[48 * 1024];    // 96 KB weight slice (linear layout)
    __shared__ float red[8][4][256];     // 32 KB K-split reduce

    const int tid  = threadIdx.x;
    const int w    = tid >> 6;          // wave 0..15
    const int tm   = w >> 1;            // m-team 0..7
    const int kh   = w & 1;             // K-half
    const int lane = tid & 63;
    const int lr   = lane & 15;
    const int kg   = lane >> 4;
    const int bid  = blockIdx.x;
    const bool isbig = (bid < 64);
    const int i0 = (isbig ? bid : bid - 64) * 16;
    const int b0 = tm * 16;
    const size_t HS = (size_t)BB * H;

    // stage whh slice -> LDS in exact wave-read order (chunk c -> byte c*16)
    auto stage = [&](const short* __restrict__ wsrc) {
        for (int c = tid; c < 6144; c += 1024) {
            int l   = c & 63;          // lane slot
            int kit = (c >> 6) & 15;   // k-iter within half
            int khh = (c >> 10) & 1;   // k-half
            int g   = c >> 11;         // gate
            const short* src = wsrc + ((size_t)(g * H + i0 + (l & 15)) << 10)
                             + khh * 512 + kit * 32 + (l >> 4) * 8;
            bf16x8 v = *(const bf16x8*)src;
            *(bf16x8*)((char*)wlds + (size_t)c * 16) = v;
        }
    };

    stage(isbig ? whh1e : whh0e);
    __syncthreads();

    for (int u = 0; u < NSTEP; ++u) {
        const bool enc = (u < TENC + 1);
        const int s = enc ? u : (u - (TENC + 1));
        if (u == TENC + 1) {           // enc -> dec weight swap (once)
            stage(isbig ? whh1d : whh0d);
            __syncthreads();
        }
        const bool act = isbig ? (s >= 1) : (enc ? s < TENC : s < TDEC);

        const short* h0b_old = y0r + (size_t)(s & 1) * HS;

        if (act) {
            f32x4 accR = {0.f, 0.f, 0.f, 0.f};
            f32x4 accZ = accR, accGN = accR, accHN = accR;
            const int k0 = kh * 512;
            const char* wl = (const char*)wlds + kh * 16384;

            if (isbig) {
                const short* h1b_old = hbf1 + (size_t)((s - 1) & 1) * HS;
                const short* wih1 = enc ? wih1e : wih1d;
                const short* ay  = h0b_old + ((size_t)(b0 + lr) << 10) + k0 + kg * 8;
                const short* ah  = h1b_old + ((size_t)(b0 + lr) << 10) + k0 + kg * 8;
                const short* wir = wih1 + ((size_t)(i0 + lr) << 10) + k0 + kg * 8;
                const short* wiz = wir + (size_t)H * H;
                const short* win = wiz + (size_t)H * H;
                #pragma unroll 2
                for (int kk = 0; kk < 512; kk += 32) {
                    const int sb = ((kk >> 5) << 10) + (lane << 4);
                    bf16x8 vy  = ald16(ay + kk);
                    bf16x8 vh  = ald16(ah + kk);
                    bf16x8 vir = *(const bf16x8*)(wir + kk);
                    bf16x8 viz = *(const bf16x8*)(wiz + kk);
                    bf16x8 vin = *(const bf16x8*)(win + kk);
                    bf16x8 whr = *(const bf16x8*)(wl + sb);
                    bf16x8 whz = *(const bf16x8*)(wl + 32768 + sb);
                    bf16x8 whn = *(const bf16x8*)(wl + 65536 + sb);
                    accR  = __builtin_amdgcn_mfma_f32_16x16x32_bf16(vy, vir, accR, 0, 0, 0);
                    accR  = __builtin_amdgcn_mfma_f32_16x16x32_bf16(vh, whr, accR, 0, 0, 0);
                    accZ  = __builtin_amdgcn_mfma_f32_16x16x32_bf16(vy, viz, accZ, 0, 0, 0);
                    accZ  = __builtin_amdgcn_mfma_f32_16x16x32_bf16(vh, whz, accZ, 0, 0, 0);
                    accGN = __builtin_amdgcn_mfma_f32_16x16x32_bf16(vy, vin, accGN, 0, 0, 0);
                    accHN = __builtin_amdgcn_mfma_f32_16x16x32_bf16(vh, whn, accHN, 0, 0, 0);
                }
            } else {
                const short* ah = h0b_old + ((size_t)(b0 + lr) << 10) + k0 + kg * 8;
                #pragma unroll 2
                for (int kk = 0; kk < 512; kk += 32) {
                    const int sb = ((kk >> 5) << 10) + (lane << 4);
                    bf16x8 a  = ald16(ah + kk);
                    bf16x8 br = *(const bf16x8*)(wl + sb);
                    bf16x8 bz = *(const bf16x8*)(wl + 32768 + sb);
                    bf16x8 bn = *(const bf16x8*)(wl + 65536 + sb);
                    accR  = __builtin_amdgcn_mfma_f32_16x16x32_bf16(a, br, accR, 0, 0, 0);
                    accZ  = __builtin_amdgcn_mfma_f32_16x16x32_bf16(a, bz, accZ, 0, 0, 0);
                    accHN = __builtin_amdgcn_mfma_f32_16x16x32_bf16(a, bn, accHN, 0, 0, 0);
                }
                if (kh == 0) {   // gi: K=32 input matmul (inputs are not state)
                    const short* x   = enc ? xencbf : decinbf;
                    const int xstride = enc ? TENC * 32 : TDEC * 32;
                    const short* wih0 = enc ? wih0e : wih0d;
                    bf16x8 a  = *(const bf16x8*)(x + (size_t)(b0 + lr) * xstride + s * 32 + kg * 8);
                    bf16x8 br = *(const bf16x8*)(wih0 + (size_t)(i0 + lr) * 32 + kg * 8);
                    bf16x8 bz = *(const bf16x8*)(wih0 + (size_t)(H + i0 + lr) * 32 + kg * 8);
                    bf16x8 bn = *(const bf16x8*)(wih0 + (size_t)(2 * H + i0 + lr) * 32 + kg * 8);
                    accR  = __builtin_amdgcn_mfma_f32_16x16x32_bf16(a, br, accR, 0, 0, 0);
                    accZ  = __builtin_amdgcn_mfma_f32_16x16x32_bf16(a, bz, accZ, 0, 0, 0);
                    accGN = __builtin_amdgcn_mfma_f32_16x16x32_bf16(a, bn, accGN, 0, 0, 0);
                }
            }
            if (kh == 1) {
                #pragma unroll
                for (int r = 0; r < 4; ++r) {
                    red[tm][0][r * 64 + lane] = accR[r];
                    red[tm][1][r * 64 + lane] = accZ[r];
                    red[tm][2][r * 64 + lane] = accGN[r];
                    red[tm][3][r * 64 + lane] = accHN[r];
                }
            }
            __syncthreads();
            if (kh == 0) {
                #pragma unroll
                for (int r = 0; r < 4; ++r) {
                    accR[r]  += red[tm][0][r * 64 + lane];
                    accZ[r]  += red[tm][1][r * 64 + lane];
                    accGN[r] += red[tm][2][r * 64 + lane];
                    accHN[r] += red[tm][3][r * 64 + lane];
                }
                const float* bih; const float* bhh;
                const float* hfo; float* hfn; short* hbn;
                if (isbig) {
                    bih = enc ? ebih1 : dbih1;  bhh = enc ? ebhh1 : dbhh1;
                    hbn = hbf1 + (size_t)(s & 1) * HS;
                    if (enc) {
                        hfo = pp1 + (size_t)((s - 1) & 1) * HS;
                        hfn = pp1 + (size_t)(s & 1) * HS;
                    } else {
                        hfo = (s == 1) ? pp1 : (y1 + (size_t)(s - 2) * HS);
                        hfn = y1 + (size_t)(s - 1) * HS;
                    }
                } else {
                    bih = enc ? ebih0 : dbih0;  bhh = enc ? ebhh0 : dbhh0;
                    hfo = pp0 + (size_t)(s & 1) * HS;
                    hfn = pp0 + (size_t)((s + 1) & 1) * HS;
                    hbn = y0r + (size_t)((s + 1) & 1) * HS;
                }
                const int col = i0 + lr;
                const float bR  = bih[col] + bhh[col];
                const float bZ  = bih[H + col] + bhh[H + col];
                const float bGN = bih[2 * H + col];
                const float bHN = bhh[2 * H + col];
                #pragma unroll
                for (int r = 0; r < 4; ++r) {
                    int row = b0 + kg * 4 + r;
                    float vr = sigmoidf_(accR[r] + bR);
                    float vz = sigmoidf_(accZ[r] + bZ);
                    float vn = tanhf(accGN[r] + bGN + vr * (accHN[r] + bHN));
                    float ho = hfo[(size_t)row * H + col];
                    float hn = (1.0f - vz) * vn + vz * ho;
                    hfn[(size_t)row * H + col] = hn;        // block-private f32
                    // bf16 state: pack adjacent cols (lr even|odd) -> u32 sc1 store
                    unsigned myb = (unsigned)(unsigned short)f2bf_rne(hn);
                    unsigned ov  = __shfl_xor(myb, 1);
                    if (!(lane & 1)) {
                        unsigned wv = myb | (ov << 16);
                        __hip_atomic_store((unsigned*)(hbn + (size_t)row * H + col),
                                           wv, __ATOMIC_RELAXED,
                                           __HIP_MEMORY_SCOPE_AGENT);
                    }
                }
            }
        } else {
            __syncthreads();   // match the reduce-phase barrier (uniform per block)
        }

        // ---- device-wide barrier: drain stores, slot store, poll, flag ----
        asm volatile("s_waitcnt vmcnt(0)" ::: "memory");
        __syncthreads();                 // all waves' stores complete
        const unsigned tgt = (unsigned)(u + 1);
        if (tid == 0)
            __hip_atomic_store(&barr[bid * 32], tgt, __ATOMIC_RELAXED,
                               __HIP_MEMORY_SCOPE_AGENT);
        if (bid == 0 && w == 0) {
            for (;;) {
                unsigned a = __hip_atomic_load(&barr[lane * 32], __ATOMIC_RELAXED,
                                               __HIP_MEMORY_SCOPE_AGENT);
                unsigned b = __hip_atomic_load(&barr[(64 + lane) * 32], __ATOMIC_RELAXED,
                                               __HIP_MEMORY_SCOPE_AGENT);
                if (__all(a >= tgt && b >= tgt)) break;
                __builtin_amdgcn_s_sleep(1);
            }
            if (lane == 0)
                __hip_atomic_store(&barr[NBLK * 32], tgt, __ATOMIC_RELAXED,
                                   __HIP_MEMORY_SCOPE_AGENT);
        } else if (tid == 0) {
            while (__hip_atomic_load(&barr[NBLK * 32], __ATOMIC_RELAXED,
                                     __HIP_MEMORY_SCOPE_AGENT) < tgt)
                __builtin_amdgcn_s_sleep(2);
        }
        __syncthreads();
    }
}

// out[b][t][o] = sum_h y1[t][b][h] * W[o][h] + bias[o]   (pure fp32)
__global__ __launch_bounds__(256) void k_proj(const float* __restrict__ y1,
                                              const float* __restrict__ W,
                                              const float* __restrict__ bias,
                                              float* __restrict__ out) {
    int idx = blockIdx.x * 256 + threadIdx.x;
    if (idx >= TDEC * BB * 32) return;
    int o = idx & 31;
    int rt = idx >> 5;        // t*BB + b
    int t = rt >> 7;
    int b = rt & (BB - 1);
    const float4* yr = (const float4*)(y1 + (size_t)rt * H);
    const float4* wr = (const float4*)(W + (size_t)o * H);
    float s = 0.f;
    #pragma unroll 4
    for (int k = 0; k < H / 4; ++k) {
        float4 a = yr[k], w = wr[k];
        s += a.x * w.x + a.y * w.y + a.z * w.z + a.w * w.w;
    }
    out[(size_t)b * TDEC * 32 + (size_t)t * 32 + o] = s + bias[o];
}

extern "C" void kernel_launch(void* const* d_in, const int* in_sizes, int n_in,
                              void* d_out, int out_size, void* d_ws, size_t ws_size,
                              hipStream_t stream) {
    const float* x_enc = (const float*)d_in[0];
    const float* x_dec = (const float*)d_in[2];
    const float* eWih0 = (const float*)d_in[4];
    const float* eWhh0 = (const float*)d_in[5];
    const float* ebih0 = (const float*)d_in[6];
    const float* ebhh0 = (const float*)d_in[7];
    const float* eWih1 = (const float*)d_in[8];
    const float* eWhh1 = (const float*)d_in[9];
    const float* ebih1 = (const float*)d_in[10];
    const float* ebhh1 = (const float*)d_in[11];
    const float* dWih0 = (const float*)d_in[12];
    const float* dWhh0 = (const float*)d_in[13];
    const float* dbih0 = (const float*)d_in[14];
    const float* dbhh0 = (const float*)d_in[15];
    const float* dWih1 = (const float*)d_in[16];
    const float* dWhh1 = (const float*)d_in[17];
    const float* dbih1 = (const float*)d_in[18];
    const float* dbhh1 = (const float*)d_in[19];
    const float* outW  = (const float*)d_in[20];
    const float* outb  = (const float*)d_in[21];
    float* out = (float*)d_out;

    char* ws = (char*)d_ws;
    size_t off = 0;
    auto alloc = [&](size_t bytes) -> void* {
        void* p = ws + off;
        off += (bytes + 255) & ~(size_t)255;
        return p;
    };
    const size_t HS = (size_t)BB * H;
    short* wih0e  = (short*)alloc((size_t)G * 32 * 2);
    short* whh0e  = (short*)alloc((size_t)G * H * 2);
    short* wih1e  = (short*)alloc((size_t)G * H * 2);
    short* whh1e  = (short*)alloc((size_t)G * H * 2);
    short* wih0d  = (short*)alloc((size_t)G * 32 * 2);
    short* whh0d  = (short*)alloc((size_t)G * H * 2);
    short* wih1d  = (short*)alloc((size_t)G * H * 2);
    short* whh1d  = (short*)alloc((size_t)G * H * 2);
    short* xencbf = (short*)alloc((size_t)BB * TENC * 32 * 2);
    short* decinbf= (short*)alloc((size_t)BB * TDEC * 32 * 2);
    short* y0r    = (short*)alloc(2 * HS * 2);
    float* pp0    = (float*)alloc(2 * HS * 4);
    short* hbf1   = (short*)alloc(2 * HS * 2);
    float* pp1    = (float*)alloc(2 * HS * 4);
    float* y1     = (float*)alloc((size_t)TDEC * HS * 4);
    unsigned* barr= (unsigned*)alloc((NBLK * 32 + 32) * 4);
    (void)ws_size; (void)in_sizes; (void)n_in; (void)out_size;

    hipMemsetAsync(y0r, 0, HS * 2, stream);
    hipMemsetAsync(pp0, 0, HS * 4, stream);
    hipMemsetAsync(hbf1, 0, HS * 2, stream);
    hipMemsetAsync(pp1, 0, HS * 4, stream);
    hipMemsetAsync(barr, 0, (NBLK * 32 + 32) * 4, stream);

    auto cvt = [&](const float* src, short* dst, int n) {
        int blocks = (n + 255) / 256;
        if (blocks > 2048) blocks = 2048;
        k_f2bf<<<dim3(blocks), dim3(256), 0, stream>>>(src, dst, n);
    };
    cvt(eWih0, wih0e, G * 32);
    cvt(eWhh0, whh0e, G * H);
    cvt(eWih1, wih1e, G * H);
    cvt(eWhh1, whh1e, G * H);
    cvt(dWih0, wih0d, G * 32);
    cvt(dWhh0, whh0d, G * H);
    cvt(dWih1, wih1d, G * H);
    cvt(dWhh1, whh1d, G * H);
    cvt(x_enc, xencbf, BB * TENC * 32);
    k_build_decin<<<dim3((BB * TDEC * 32 + 255) / 256), dim3(256), 0, stream>>>(
        x_enc, x_dec, decinbf);

    k_persist<<<dim3(NBLK), dim3(1024), 0, stream>>>(
        xencbf, decinbf,
        wih0e, whh0e, ebih0, ebhh0, wih1e, whh1e, ebih1, ebhh1,
        wih0d, whh0d, dbih0, dbhh0, wih1d, whh1d, dbih1, dbhh1,
        y0r, pp0, hbf1, pp1, y1, barr);

    k_proj<<<dim3((TDEC * BB * 32 + 255) / 256), dim3(256), 0, stream>>>(
        y1, outW, outb, out);
}

// Round 7
// 8039.958 us; speedup vs baseline: 1.9569x; 1.9569x over previous
//
#include <hip/hip_runtime.h>
#include <hip/hip_bf16.h>

// Seq2seq GRU (2-layer enc T=192, 2-layer dec T=96), B=128, H=1024.
// Round 7: back to launch-per-step (best measured regime). 3-stage diagonal
// pipeline per launch: z=0 L0[s], z=1 gi1[s-1]=y0@Wih1^T, z=2 L1[s-2]
// (recurrent-only + gi from f32 ring). All cells balanced: 4 load streams,
// 3 MFMA/iter, K-split-2 (2 waves/wg, LDS reduce), 12 waves/CU.
// bf16 MFMA (fp32 accum), fp32 master hidden state, fp32 projection.

#define H 1024
#define G 3072   /* 3*H */
#define BB 128
#define TENC 192
#define TDEC 96

typedef __attribute__((ext_vector_type(4))) float f32x4;
typedef __attribute__((ext_vector_type(8))) short bf16x8;

#define MFMA16(a, b, c) __builtin_amdgcn_mfma_f32_16x16x32_bf16(a, b, c, 0, 0, 0)

__device__ __forceinline__ float sigmoidf_(float x) {
    return 1.0f / (1.0f + __expf(-x));
}

__device__ __forceinline__ short f2bf_rne(float f) {
    union { float f; unsigned u; } v; v.f = f;
    unsigned r = v.u + 0x7fffu + ((v.u >> 16) & 1u);
    return (short)(r >> 16);
}

__global__ __launch_bounds__(256) void k_f2bf(const float* __restrict__ in,
                                              short* __restrict__ out, int n) {
    for (int i = blockIdx.x * 256 + threadIdx.x; i < n; i += gridDim.x * 256)
        out[i] = f2bf_rne(in[i]);
}

// dec_in[b][t][c]: t==0 -> x_enc[b][191][c], else x_dec[b][t-1][c]
__global__ __launch_bounds__(256) void k_build_decin(const float* __restrict__ x_enc,
                                                     const float* __restrict__ x_dec,
                                                     short* __restrict__ out) {
    int i = blockIdx.x * 256 + threadIdx.x;
    if (i >= BB * TDEC * 32) return;
    int c = i & 31;
    int t = (i >> 5) % TDEC;
    int b = i / (TDEC * 32);
    float v = (t == 0) ? x_enc[(size_t)b * TENC * 32 + 191 * 32 + c]
                       : x_dec[(size_t)b * TDEC * 32 + (t - 1) * 32 + c];
    out[i] = f2bf_rne(v);
}

// One diagonal pipeline step. grid (64 i-tiles, 8 b-tiles, 3 roles), 128 thr.
// Ring parity: state produced at time t lives in slot t&1.
__global__ __launch_bounds__(128) void k_step3(
    int s, int enc,
    const short* __restrict__ xbf, int xstride,
    const short* __restrict__ wih0, const short* __restrict__ whh0,
    const float* __restrict__ bih0, const float* __restrict__ bhh0,
    const short* __restrict__ wih1, const short* __restrict__ whh1,
    const float* __restrict__ bih1, const float* __restrict__ bhh1,
    short* __restrict__ y0r, float* __restrict__ pp0,
    float* __restrict__ gibuf,
    short* __restrict__ hbf1, float* __restrict__ pp1,
    float* __restrict__ y1)
{
    __shared__ float red[4][256];
    const int tid  = threadIdx.x;
    const int kh   = tid >> 6;          // K-half (wave)
    const int lane = tid & 63;
    const int lr   = lane & 15;
    const int kg   = lane >> 4;
    const int i0   = blockIdx.x * 16;
    const int b0   = blockIdx.y * 16;
    const int z    = blockIdx.z;
    const int T    = enc ? TENC : TDEC;
    const size_t HS  = (size_t)BB * H;
    const size_t GIS = (size_t)3 * BB * H;
    const int k0 = kh * 512;
    const int col = i0 + lr;

    f32x4 accR = {0.f, 0.f, 0.f, 0.f};
    f32x4 accZ = accR, accGN = accR, accHN = accR;

    if (z == 0) {
        // ---- L0 cell at t = s ----
        const int t = s;
        if (t >= T) return;
        const int rds = (t == 0) ? 1 : ((t - 1) & 1);
        const short* ah = y0r + (size_t)rds * HS + ((size_t)(b0 + lr) << 10) + k0 + kg * 8;
        const short* wr = whh0 + ((size_t)(i0 + lr) << 10) + k0 + kg * 8;
        const short* wz = wr + (size_t)H * H;
        const short* wn = wz + (size_t)H * H;
        #pragma unroll 4
        for (int kk = 0; kk < 512; kk += 32) {
            bf16x8 a  = *(const bf16x8*)(ah + kk);
            bf16x8 br = *(const bf16x8*)(wr + kk);
            bf16x8 bz = *(const bf16x8*)(wz + kk);
            bf16x8 bn = *(const bf16x8*)(wn + kk);
            accR  = MFMA16(a, br, accR);
            accZ  = MFMA16(a, bz, accZ);
            accHN = MFMA16(a, bn, accHN);
        }
        if (kh == 0) {   // gi0: K=32 input matmul
            bf16x8 a  = *(const bf16x8*)(xbf + (size_t)(b0 + lr) * xstride + t * 32 + kg * 8);
            bf16x8 br = *(const bf16x8*)(wih0 + (size_t)(i0 + lr) * 32 + kg * 8);
            bf16x8 bz = *(const bf16x8*)(wih0 + (size_t)(H + i0 + lr) * 32 + kg * 8);
            bf16x8 bn = *(const bf16x8*)(wih0 + (size_t)(2 * H + i0 + lr) * 32 + kg * 8);
            accR  = MFMA16(a, br, accR);
            accZ  = MFMA16(a, bz, accZ);
            accGN = MFMA16(a, bn, accGN);
        }
        if (kh == 1) {
            #pragma unroll
            for (int r = 0; r < 4; ++r) {
                red[0][r * 64 + lane] = accR[r];
                red[1][r * 64 + lane] = accZ[r];
                red[2][r * 64 + lane] = accGN[r];
                red[3][r * 64 + lane] = accHN[r];
            }
        }
        __syncthreads();
        if (kh == 0) {
            const float* hfo = pp0 + (size_t)rds * HS;
            float*       hfn = pp0 + (size_t)(t & 1) * HS;
            short*       hbn = y0r + (size_t)(t & 1) * HS;
            const float bR  = bih0[col] + bhh0[col];
            const float bZ  = bih0[H + col] + bhh0[H + col];
            const float bGN = bih0[2 * H + col];
            const float bHN = bhh0[2 * H + col];
            #pragma unroll
            for (int r = 0; r < 4; ++r) {
                int row = b0 + kg * 4 + r;
                float aR  = accR[r]  + red[0][r * 64 + lane];
                float aZ  = accZ[r]  + red[1][r * 64 + lane];
                float aGN = accGN[r] + red[2][r * 64 + lane];
                float aHN = accHN[r] + red[3][r * 64 + lane];
                float vr = sigmoidf_(aR + bR);
                float vz = sigmoidf_(aZ + bZ);
                float vn = tanhf(aGN + bGN + vr * (aHN + bHN));
                float ho = hfo[(size_t)row * H + col];
                float hn = (1.0f - vz) * vn + vz * ho;
                hfn[(size_t)row * H + col] = hn;
                hbn[(size_t)row * H + col] = f2bf_rne(hn);
            }
        }
    } else if (z == 1) {
        // ---- gi1 stream at t = s-1: gi1[t] = y0[t] @ Wih1^T (3 gates) ----
        const int t = s - 1;
        if (t < 0 || t >= T) return;
        const short* ay = y0r + (size_t)(t & 1) * HS + ((size_t)(b0 + lr) << 10) + k0 + kg * 8;
        const short* wr = wih1 + ((size_t)(i0 + lr) << 10) + k0 + kg * 8;
        const short* wz = wr + (size_t)H * H;
        const short* wn = wz + (size_t)H * H;
        #pragma unroll 4
        for (int kk = 0; kk < 512; kk += 32) {
            bf16x8 a  = *(const bf16x8*)(ay + kk);
            bf16x8 br = *(const bf16x8*)(wr + kk);
            bf16x8 bz = *(const bf16x8*)(wz + kk);
            bf16x8 bn = *(const bf16x8*)(wn + kk);
            accR = MFMA16(a, br, accR);
            accZ = MFMA16(a, bz, accZ);
            accGN= MFMA16(a, bn, accGN);
        }
        if (kh == 1) {
            #pragma unroll
            for (int r = 0; r < 4; ++r) {
                red[0][r * 64 + lane] = accR[r];
                red[1][r * 64 + lane] = accZ[r];
                red[2][r * 64 + lane] = accGN[r];
            }
        }
        __syncthreads();
        if (kh == 0) {
            float* gio = gibuf + (size_t)(t & 1) * GIS;
            #pragma unroll
            for (int r = 0; r < 4; ++r) {
                int row = b0 + kg * 4 + r;
                gio[((size_t)(0 * BB + row) << 10) + col] = accR[r]  + red[0][r * 64 + lane];
                gio[((size_t)(1 * BB + row) << 10) + col] = accZ[r]  + red[1][r * 64 + lane];
                gio[((size_t)(2 * BB + row) << 10) + col] = accGN[r] + red[2][r * 64 + lane];
            }
        }
    } else {
        // ---- L1 cell at t = s-2: recurrent matmul only + gi from ring ----
        const int t = s - 2;
        if (t < 0 || t >= T) return;
        const int rds = (t == 0) ? 1 : ((t - 1) & 1);
        const short* ah = hbf1 + (size_t)rds * HS + ((size_t)(b0 + lr) << 10) + k0 + kg * 8;
        const short* wr = whh1 + ((size_t)(i0 + lr) << 10) + k0 + kg * 8;
        const short* wz = wr + (size_t)H * H;
        const short* wn = wz + (size_t)H * H;
        #pragma unroll 4
        for (int kk = 0; kk < 512; kk += 32) {
            bf16x8 a  = *(const bf16x8*)(ah + kk);
            bf16x8 br = *(const bf16x8*)(wr + kk);
            bf16x8 bz = *(const bf16x8*)(wz + kk);
            bf16x8 bn = *(const bf16x8*)(wn + kk);
            accR  = MFMA16(a, br, accR);
            accZ  = MFMA16(a, bz, accZ);
            accHN = MFMA16(a, bn, accHN);
        }
        if (kh == 1) {
            #pragma unroll
            for (int r = 0; r < 4; ++r) {
                red[0][r * 64 + lane] = accR[r];
                red[1][r * 64 + lane] = accZ[r];
                red[2][r * 64 + lane] = accHN[r];
            }
        }
        __syncthreads();
        if (kh == 0) {
            const float* gii = gibuf + (size_t)(t & 1) * GIS;
            const float* hfo = (t == 0) ? (pp1 + HS)
                             : (enc ? (pp1 + (size_t)((t - 1) & 1) * HS)
                                    : (y1 + (size_t)(t - 1) * HS));
            float* hfn = enc ? (pp1 + (size_t)(t & 1) * HS)
                             : (y1 + (size_t)t * HS);
            short* hbn = hbf1 + (size_t)(t & 1) * HS;
            const float bR  = bih1[col] + bhh1[col];
            const float bZ  = bih1[H + col] + bhh1[H + col];
            const float bGN = bih1[2 * H + col];
            const float bHN = bhh1[2 * H + col];
            #pragma unroll
            for (int r = 0; r < 4; ++r) {
                int row = b0 + kg * 4 + r;
                float aR  = accR[r]  + red[0][r * 64 + lane];
                float aZ  = accZ[r]  + red[1][r * 64 + lane];
                float aHN = accHN[r] + red[2][r * 64 + lane];
                float gR  = gii[((size_t)(0 * BB + row) << 10) + col];
                float gZ  = gii[((size_t)(1 * BB + row) << 10) + col];
                float gN  = gii[((size_t)(2 * BB + row) << 10) + col];
                float vr = sigmoidf_(aR + gR + bR);
                float vz = sigmoidf_(aZ + gZ + bZ);
                float vn = tanhf(gN + bGN + vr * (aHN + bHN));
                float ho = hfo[(size_t)row * H + col];
                float hn = (1.0f - vz) * vn + vz * ho;
                hfn[(size_t)row * H + col] = hn;
                hbn[(size_t)row * H + col] = f2bf_rne(hn);
            }
        }
    }
}

// out[b][t][o] = sum_h y1[t][b][h] * W[o][h] + bias[o]   (pure fp32)
__global__ __launch_bounds__(256) void k_proj(const float* __restrict__ y1,
                                              const float* __restrict__ W,
                                              const float* __restrict__ bias,
                                              float* __restrict__ out) {
    int idx = blockIdx.x * 256 + threadIdx.x;
    if (idx >= TDEC * BB * 32) return;
    int o = idx & 31;
    int rt = idx >> 5;        // t*BB + b
    int t = rt >> 7;
    int b = rt & (BB - 1);
    const float4* yr = (const float4*)(y1 + (size_t)rt * H);
    const float4* wr = (const float4*)(W + (size_t)o * H);
    float s = 0.f;
    #pragma unroll 4
    for (int k = 0; k < H / 4; ++k) {
        float4 a = yr[k], w = wr[k];
        s += a.x * w.x + a.y * w.y + a.z * w.z + a.w * w.w;
    }
    out[(size_t)b * TDEC * 32 + (size_t)t * 32 + o] = s + bias[o];
}

extern "C" void kernel_launch(void* const* d_in, const int* in_sizes, int n_in,
                              void* d_out, int out_size, void* d_ws, size_t ws_size,
                              hipStream_t stream) {
    const float* x_enc = (const float*)d_in[0];
    const float* x_dec = (const float*)d_in[2];
    const float* eWih0 = (const float*)d_in[4];
    const float* eWhh0 = (const float*)d_in[5];
    const float* ebih0 = (const float*)d_in[6];
    const float* ebhh0 = (const float*)d_in[7];
    const float* eWih1 = (const float*)d_in[8];
    const float* eWhh1 = (const float*)d_in[9];
    const float* ebih1 = (const float*)d_in[10];
    const float* ebhh1 = (const float*)d_in[11];
    const float* dWih0 = (const float*)d_in[12];
    const float* dWhh0 = (const float*)d_in[13];
    const float* dbih0 = (const float*)d_in[14];
    const float* dbhh0 = (const float*)d_in[15];
    const float* dWih1 = (const float*)d_in[16];
    const float* dWhh1 = (const float*)d_in[17];
    const float* dbih1 = (const float*)d_in[18];
    const float* dbhh1 = (const float*)d_in[19];
    const float* outW  = (const float*)d_in[20];
    const float* outb  = (const float*)d_in[21];
    float* out = (float*)d_out;

    char* ws = (char*)d_ws;
    size_t off = 0;
    auto alloc = [&](size_t bytes) -> void* {
        void* p = ws + off;
        off += (bytes + 255) & ~(size_t)255;
        return p;
    };
    const size_t HS = (size_t)BB * H;
    short* wih0e  = (short*)alloc((size_t)G * 32 * 2);
    short* whh0e  = (short*)alloc((size_t)G * H * 2);
    short* wih1e  = (short*)alloc((size_t)G * H * 2);
    short* whh1e  = (short*)alloc((size_t)G * H * 2);
    short* wih0d  = (short*)alloc((size_t)G * 32 * 2);
    short* whh0d  = (short*)alloc((size_t)G * H * 2);
    short* wih1d  = (short*)alloc((size_t)G * H * 2);
    short* whh1d  = (short*)alloc((size_t)G * H * 2);
    short* xencbf = (short*)alloc((size_t)BB * TENC * 32 * 2);
    short* decinbf= (short*)alloc((size_t)BB * TDEC * 32 * 2);
    short* y0r    = (short*)alloc(2 * HS * 2);
    float* pp0    = (float*)alloc(2 * HS * 4);
    short* hbf1   = (short*)alloc(2 * HS * 2);
    float* pp1    = (float*)alloc(2 * HS * 4);
    float* gibuf  = (float*)alloc(2 * 3 * HS * 4);
    float* y1     = (float*)alloc((size_t)TDEC * HS * 4);
    (void)ws_size; (void)in_sizes; (void)n_in; (void)out_size;

    // zero-init rings (slot 1 must be zero for t==0 reads)
    hipMemsetAsync(y0r, 0, 2 * HS * 2, stream);
    hipMemsetAsync(pp0, 0, 2 * HS * 4, stream);
    hipMemsetAsync(hbf1, 0, 2 * HS * 2, stream);
    hipMemsetAsync(pp1, 0, 2 * HS * 4, stream);

    auto cvt = [&](const float* src, short* dst, int n) {
        int blocks = (n + 255) / 256;
        if (blocks > 2048) blocks = 2048;
        k_f2bf<<<dim3(blocks), dim3(256), 0, stream>>>(src, dst, n);
    };
    cvt(eWih0, wih0e, G * 32);
    cvt(eWhh0, whh0e, G * H);
    cvt(eWih1, wih1e, G * H);
    cvt(eWhh1, whh1e, G * H);
    cvt(dWih0, wih0d, G * 32);
    cvt(dWhh0, whh0d, G * H);
    cvt(dWih1, wih1d, G * H);
    cvt(dWhh1, whh1d, G * H);
    cvt(x_enc, xencbf, BB * TENC * 32);
    k_build_decin<<<dim3((BB * TDEC * 32 + 255) / 256), dim3(256), 0, stream>>>(
        x_enc, x_dec, decinbf);

    const dim3 dg(64, 8, 3), db(128);
    // encoder: s = 0 .. TENC+1
    for (int s = 0; s <= TENC + 1; ++s)
        k_step3<<<dg, db, 0, stream>>>(s, 1, xencbf, TENC * 32,
            wih0e, whh0e, ebih0, ebhh0, wih1e, whh1e, ebih1, ebhh1,
            y0r, pp0, gibuf, hbf1, pp1, y1);
    // decoder: s = 0 .. TDEC+1
    for (int s = 0; s <= TDEC + 1; ++s)
        k_step3<<<dg, db, 0, stream>>>(s, 0, decinbf, TDEC * 32,
            wih0d, whh0d, dbih0, dbhh0, wih1d, whh1d, dbih1, dbhh1,
            y0r, pp0, gibuf, hbf1, pp1, y1);

    k_proj<<<dim3((TDEC * BB * 32 + 255) / 256), dim3(256), 0, stream>>>(
        y1, outW, outb, out);
}